// Round 13
// baseline (372.392 us; speedup 1.0000x reference)
//
#include <hip/hip_runtime.h>

typedef __attribute__((ext_vector_type(8))) short bf16x8;
typedef __attribute__((ext_vector_type(4))) float f32x4;

constexpr int B  = 16;
constexpr int H  = 64;
constexpr int W  = 64;
constexpr int C  = 256;
constexpr int NH = 8;
constexpr int KD = 32;
constexpr float SCALE = 0.17677669529663687f; // 32^-0.5
constexpr int M_TOT = B * H * W;              // 65536
constexpr size_t NEL = (size_t)B * H * W * C; // 16777216

__device__ __forceinline__ unsigned short f2bf(float f) {
    union { float f; unsigned int u; } x; x.f = f;
    unsigned int u = x.u;
    unsigned int r = (u + 0x7fffu + ((u >> 16) & 1u)) >> 16;
    return (unsigned short)r;
}
__device__ __forceinline__ float bf2f(unsigned short s) {
    union { unsigned int u; float f; } x; x.u = ((unsigned int)s) << 16; return x.f;
}
__device__ __forceinline__ float bf_lo(unsigned int u) {
    union { unsigned int u; float f; } x; x.u = u << 16; return x.f;
}
__device__ __forceinline__ float bf_hi(unsigned int u) {
    union { unsigned int u; float f; } x; x.u = u & 0xffff0000u; return x.f;
}
__device__ __forceinline__ unsigned int pack2(float a, float b) {
    return (unsigned int)f2bf(a) | ((unsigned int)f2bf(b) << 16);
}
__device__ __forceinline__ void cvt8(uint4 rv, float* f) {
    f[0] = bf_lo(rv.x); f[1] = bf_hi(rv.x); f[2] = bf_lo(rv.y); f[3] = bf_hi(rv.y);
    f[4] = bf_lo(rv.z); f[5] = bf_hi(rv.z); f[6] = bf_lo(rv.w); f[7] = bf_hi(rv.w);
}
// LDS chunk swizzle (write-side + read-side, value-consistent)
__device__ __forceinline__ int swz(int row, int kp8) {
    return row * 32 + (kp8 ^ (((row >> 2) & 3) << 3));
}

// ---------------------------------------------------------------------------
// prep: x fp32 -> bf16
// ---------------------------------------------------------------------------
__global__ __launch_bounds__(256) void prep_x16(const float* __restrict__ x,
                                                unsigned short* __restrict__ x16) {
    size_t i8 = ((size_t)blockIdx.x * 256 + threadIdx.x) * 8;
    float4 f0 = *(const float4*)(x + i8);
    float4 f1 = *(const float4*)(x + i8 + 4);
    uint4 o;
    o.x = pack2(f0.x, f0.y); o.y = pack2(f0.z, f0.w);
    o.z = pack2(f1.x, f1.y); o.w = pack2(f1.z, f1.w);
    *(uint4*)(x16 + i8) = o;
}

// ---------------------------------------------------------------------------
// prep: W (256k x 256n fp32) -> Wt16[n][k] bf16 (n-major)
// ---------------------------------------------------------------------------
__global__ __launch_bounds__(256) void trans_w(const float* __restrict__ src,
                                               unsigned short* __restrict__ dst) {
    int tid = blockIdx.x * 256 + threadIdx.x;   // 0..8191
    int n = tid >> 5, k0 = (tid & 31) << 3;
    unsigned int p[4];
#pragma unroll
    for (int j = 0; j < 4; ++j) {
        float a  = src[(size_t)(k0 + 2 * j) * 256 + n];
        float b2 = src[(size_t)(k0 + 2 * j + 1) * 256 + n];
        p[j] = pack2(a, b2);
    }
    uint4 o = {p[0], p[1], p[2], p[3]};
    *(uint4*)(dst + (size_t)n * 256 + k0) = o;
}

// ---------------------------------------------------------------------------
// Kernel 1: fused QKV MFMA GEMM, BK=64 (32 MFMA per barrier pair).
// 1D grid: yb = bid%6 (n-block; 6 variants of one m-stripe adjacent -> L2/L3
// x-reuse), mb = bid/6. Swapped MFMA: C[row->n][col->m].
// yb 0..3 = q,k halves (in-lane rotary); yb 4..5 = v.
// ---------------------------------------------------------------------------
__global__ __launch_bounds__(256) void qkv_mfma(
    const unsigned short* __restrict__ x16, const unsigned short* __restrict__ Wt16,
    const float* __restrict__ bq, const float* __restrict__ bk, const float* __restrict__ bv,
    const float* __restrict__ sin_t, const float* __restrict__ cos_t,
    unsigned short* __restrict__ qr, unsigned short* __restrict__ kr,
    unsigned short* __restrict__ v16)
{
    __shared__ __align__(16) unsigned short As[2][128 * 32];
    __shared__ __align__(16) unsigned short Bs[2][128 * 32];

    const int t = threadIdx.x;
    const int lane = t & 63, wid = t >> 6;
    const int wr = wid >> 1, wc = wid & 1;
    const int bid = blockIdx.x;
    const int yb = bid % 6;
    const int m0 = (bid / 6) * 128;
    const int n0 = yb * 128;                  // Wt16 row base (0..640)
    const int matid = yb >> 1;                // 0=q 1=k 2=v
    const int nb = n0 & 255;                  // within-matrix n base

    f32x4 acc[4][4];
#pragma unroll
    for (int i = 0; i < 4; ++i)
#pragma unroll
        for (int j = 0; j < 4; ++j)
#pragma unroll
            for (int q = 0; q < 4; ++q) acc[i][j][q] = 0.f;

    const int row_s = t >> 2;            // 0..63
    const int kp_s  = (t & 3) << 3;      // 0,8,16,24

    for (int ks = 0; ks < 4; ++ks) {
        const int k0 = ks * 64;
        uint4 a[2][2], b2[2][2];
#pragma unroll
        for (int h2 = 0; h2 < 2; ++h2) {
            const unsigned short* ap = x16 + (size_t)(m0 + row_s) * 256 + k0 + h2 * 32 + kp_s;
            a[h2][0] = *(const uint4*)ap;
            a[h2][1] = *(const uint4*)(ap + 64 * 256);
            const unsigned short* bp = Wt16 + (size_t)(n0 + row_s) * 256 + k0 + h2 * 32 + kp_s;
            b2[h2][0] = *(const uint4*)bp;
            b2[h2][1] = *(const uint4*)(bp + 64 * 256);
        }

        __syncthreads();
#pragma unroll
        for (int h2 = 0; h2 < 2; ++h2) {
            *(uint4*)(&As[h2][swz(row_s,      kp_s)]) = a[h2][0];
            *(uint4*)(&As[h2][swz(row_s + 64, kp_s)]) = a[h2][1];
            *(uint4*)(&Bs[h2][swz(row_s,      kp_s)]) = b2[h2][0];
            *(uint4*)(&Bs[h2][swz(row_s + 64, kp_s)]) = b2[h2][1];
        }
        __syncthreads();

        const int rsel = lane & 15, kg8 = (lane >> 4) << 3;
#pragma unroll
        for (int h2 = 0; h2 < 2; ++h2) {
            bf16x8 af[4], bf[4];
#pragma unroll
            for (int i = 0; i < 4; ++i)
                af[i] = *(const bf16x8*)(&As[h2][swz(wr * 64 + i * 16 + rsel, kg8)]);
#pragma unroll
            for (int j = 0; j < 4; ++j)
                bf[j] = *(const bf16x8*)(&Bs[h2][swz(wc * 64 + j * 16 + rsel, kg8)]);
            // swapped: C[row->n][col->m]
#pragma unroll
            for (int i = 0; i < 4; ++i)
#pragma unroll
                for (int j = 0; j < 4; ++j)
                    acc[i][j] = __builtin_amdgcn_mfma_f32_16x16x32_bf16(bf[j], af[i], acc[i][j], 0, 0, 0);
        }
    }

    const int col_l = lane & 15, rowg = (lane >> 4) << 2;
    if (matid == 2) {
        // v: lane holds 4 consecutive n at row m -> ushort4 store
#pragma unroll
        for (int i = 0; i < 4; ++i) {
            const int m = m0 + wr * 64 + i * 16 + col_l;
#pragma unroll
            for (int j = 0; j < 4; ++j) {
                const int nn = nb + wc * 64 + j * 16 + rowg;
                float4 bias4 = *(const float4*)(bv + nn);
                ushort4 o;
                o.x = f2bf(acc[i][j][0] + bias4.x);
                o.y = f2bf(acc[i][j][1] + bias4.y);
                o.z = f2bf(acc[i][j][2] + bias4.z);
                o.w = f2bf(acc[i][j][3] + bias4.w);
                *(ushort4*)(v16 + (size_t)m * 256 + nn) = o;
            }
        }
    } else {
        // q/k: lane holds 4 consecutive d -> in-lane rotary, 8B stores
        const float sc = matid ? SCALE : 1.0f;
        const float* __restrict__ bias = matid ? bk : bq;
        unsigned short* __restrict__ dst = matid ? kr : qr;
#pragma unroll
        for (int i = 0; i < 4; ++i) {
            const int m = m0 + wr * 64 + i * 16 + col_l;
            const int bb = m >> 12, hh = (m >> 6) & 63, ww = m & 63;
            const size_t pixbase = ((size_t)hh * 64 + ww) * 32;
#pragma unroll
            for (int j = 0; j < 4; ++j) {
                const int n = nb + wc * 64 + j * 16 + rowg;  // 4 consecutive n
                const int nh = n >> 5, db = n & 31;
                float4 bias4 = *(const float4*)(bias + n);
                float4 cs4 = *(const float4*)(cos_t + pixbase + db);
                float4 sn4 = *(const float4*)(sin_t + pixbase + db);
                float v0 = (acc[i][j][0] + bias4.x) * sc;
                float v1 = (acc[i][j][1] + bias4.y) * sc;
                float v2 = (acc[i][j][2] + bias4.z) * sc;
                float v3 = (acc[i][j][3] + bias4.w) * sc;
                ushort4 o;
                o.x = f2bf(v0 * cs4.x - v1 * sn4.x);
                o.y = f2bf(v1 * cs4.y + v0 * sn4.y);
                o.z = f2bf(v2 * cs4.z - v3 * sn4.z);
                o.w = f2bf(v3 * cs4.w + v2 * sn4.w);
                *(ushort4*)(dst + ((((size_t)bb * 8 + nh) * 64 + hh) * 64 + ww) * 32 + db) = o;
            }
        }
    }
}

// ---------------------------------------------------------------------------
// Kernel 2: 5x5 depthwise conv (lepe), bf16 in/out.
// Each thread: 8 channels x 4 consecutive w. Row-register reuse across taps.
// ---------------------------------------------------------------------------
__global__ __launch_bounds__(256) void conv_kernel(
    const unsigned short* __restrict__ v, const float* __restrict__ cw,
    const float* __restrict__ cb, unsigned short* __restrict__ lepe)
{
    size_t tid = (size_t)blockIdx.x * 256 + threadIdx.x;   // 512K threads
    const int c8 = (int)(tid & 31) << 3;          // channel group of 8
    const int w0 = ((int)(tid >> 5) & 15) << 2;   // 0,4,..,60
    const int h  = (int)(tid >> 9) & 63;
    const int b  = (int)(tid >> 15);

    float acc[4][8];
    {
        float4 cb0 = *(const float4*)(cb + c8);
        float4 cb1 = *(const float4*)(cb + c8 + 4);
#pragma unroll
        for (int o = 0; o < 4; ++o) {
            acc[o][0] = cb0.x; acc[o][1] = cb0.y; acc[o][2] = cb0.z; acc[o][3] = cb0.w;
            acc[o][4] = cb1.x; acc[o][5] = cb1.y; acc[o][6] = cb1.z; acc[o][7] = cb1.w;
        }
    }

    const unsigned short* __restrict__ vb = v + (size_t)b * 4096 * 256 + c8;
#pragma unroll
    for (int dy = 0; dy < 5; ++dy) {
        const int yy = h + dy - 2;
        if (yy < 0 || yy >= 64) continue;
        float rowf[8][8];
#pragma unroll
        for (int j = 0; j < 8; ++j) {
            const int xx = w0 + j - 2;
            if (xx < 0 || xx >= 64) {
#pragma unroll
                for (int q = 0; q < 8; ++q) rowf[j][q] = 0.f;
            } else {
                uint4 rv = *(const uint4*)(vb + (size_t)(yy * 64 + xx) * 256);
                cvt8(rv, rowf[j]);
            }
        }
#pragma unroll
        for (int dx = 0; dx < 5; ++dx) {
            const float* wp = cw + (dy * 5 + dx) * 256 + c8;
            float4 wv0 = *(const float4*)wp;
            float4 wv1 = *(const float4*)(wp + 4);
#pragma unroll
            for (int o = 0; o < 4; ++o) {
                const float* rf = rowf[dx + o];
                acc[o][0] += rf[0] * wv0.x; acc[o][1] += rf[1] * wv0.y;
                acc[o][2] += rf[2] * wv0.z; acc[o][3] += rf[3] * wv0.w;
                acc[o][4] += rf[4] * wv1.x; acc[o][5] += rf[5] * wv1.y;
                acc[o][6] += rf[6] * wv1.z; acc[o][7] += rf[7] * wv1.w;
            }
        }
    }

    unsigned short* __restrict__ op = lepe + (((size_t)(b * 64 + h) * 64) + w0) * 256 + c8;
#pragma unroll
    for (int o = 0; o < 4; ++o) {
        uint4 ov;
        ov.x = pack2(acc[o][0], acc[o][1]); ov.y = pack2(acc[o][2], acc[o][3]);
        ov.z = pack2(acc[o][4], acc[o][5]); ov.w = pack2(acc[o][6], acc[o][7]);
        *(uint4*)(op + (size_t)o * 256) = ov;
    }
}

// ---------------------------------------------------------------------------
// Kernel 3/4: MFMA attention along one axis. One block per (b,pos,nh).
// ---------------------------------------------------------------------------
template <int AXIS>
__global__ __launch_bounds__(256) void attn_mfma(
    const unsigned short* __restrict__ qr, const unsigned short* __restrict__ kr,
    const unsigned short* __restrict__ vin, const float* __restrict__ mask,
    const unsigned short* __restrict__ addin, unsigned short* __restrict__ outp)
{
    __shared__ __align__(16) short qs[64 * 40];
    __shared__ __align__(16) short ks[64 * 40];
    __shared__ __align__(16) short vt[32 * 72];
    __shared__ __align__(16) short P [64 * 72];

    const int t    = threadIdx.x;
    const int lane = t & 63, wv = t >> 6;
    const int bid  = blockIdx.x;
    const int nh   = bid & 7;
    const int pos  = (bid >> 3) & 63;
    const int b    = bid >> 9;

    size_t qbase, vbase;
    int qstride, vstride;
    if (AXIS == 0) {
        qbase   = ((size_t)(b * 8 + nh) * 64 + pos) * 2048;
        qstride = 32;
        vbase   = ((size_t)(b * 64 + pos) * 64) * 256 + nh * 32;
        vstride = 256;
    } else {
        qbase   = ((size_t)(b * 8 + nh) * 64) * 2048 + pos * 32;
        qstride = 2048;
        vbase   = ((size_t)b * 64 * 64) * 256 + pos * 256 + nh * 32;
        vstride = 16384;
    }

    {
        int row = t >> 2, c8 = (t & 3) << 3;
        uint4 rq = *(const uint4*)(qr + qbase + (size_t)row * qstride + c8);
        *(uint4*)(&qs[row * 40 + c8]) = rq;
        uint4 rk = *(const uint4*)(kr + qbase + (size_t)row * qstride + c8);
        *(uint4*)(&ks[row * 40 + c8]) = rk;
        uint4 rv = *(const uint4*)(vin + vbase + (size_t)row * vstride + c8);
        const unsigned short* pv = (const unsigned short*)&rv;
#pragma unroll
        for (int j = 0; j < 8; ++j) vt[(c8 + j) * 72 + row] = pv[j];
    }
    __syncthreads();

    const int rsel = lane & 15;
    const int kg   = (lane >> 4) << 3;
    const int rowg = (lane >> 4) << 2;

    bf16x8 aq = *(const bf16x8*)(&qs[(wv * 16 + rsel) * 40 + kg]);
    f32x4 s[4];
#pragma unroll
    for (int j = 0; j < 4; ++j) {
        f32x4 z = {0.f, 0.f, 0.f, 0.f};
        bf16x8 bk8 = *(const bf16x8*)(&ks[(j * 16 + rsel) * 40 + kg]);
        s[j] = __builtin_amdgcn_mfma_f32_16x16x32_bf16(aq, bk8, z, 0, 0, 0);
    }

    const float* __restrict__ mrow = mask + (size_t)nh * 4096;
#pragma unroll
    for (int r = 0; r < 4; ++r) {
        const int grow = wv * 16 + rowg + r;
#pragma unroll
        for (int j = 0; j < 4; ++j)
            s[j][r] += mrow[grow * 64 + j * 16 + rsel];
        float mx = fmaxf(fmaxf(s[0][r], s[1][r]), fmaxf(s[2][r], s[3][r]));
        mx = fmaxf(mx, __shfl_xor(mx, 1));
        mx = fmaxf(mx, __shfl_xor(mx, 2));
        mx = fmaxf(mx, __shfl_xor(mx, 4));
        mx = fmaxf(mx, __shfl_xor(mx, 8));
        float e0 = __expf(s[0][r] - mx), e1 = __expf(s[1][r] - mx);
        float e2 = __expf(s[2][r] - mx), e3 = __expf(s[3][r] - mx);
        float sum = e0 + e1 + e2 + e3;
        sum += __shfl_xor(sum, 1);
        sum += __shfl_xor(sum, 2);
        sum += __shfl_xor(sum, 4);
        sum += __shfl_xor(sum, 8);
        float inv = 1.0f / sum;
        P[grow * 72 +      rsel] = f2bf(e0 * inv);
        P[grow * 72 + 16 + rsel] = f2bf(e1 * inv);
        P[grow * 72 + 32 + rsel] = f2bf(e2 * inv);
        P[grow * 72 + 48 + rsel] = f2bf(e3 * inv);
    }
    __syncthreads();

    f32x4 o[2];
#pragma unroll
    for (int n = 0; n < 2; ++n)
#pragma unroll
        for (int q = 0; q < 4; ++q) o[n][q] = 0.f;
#pragma unroll
    for (int kk = 0; kk < 2; ++kk) {
        bf16x8 ap = *(const bf16x8*)(&P[(wv * 16 + rsel) * 72 + kk * 32 + kg]);
#pragma unroll
        for (int n = 0; n < 2; ++n) {
            bf16x8 bv8 = *(const bf16x8*)(&vt[(n * 16 + rsel) * 72 + kk * 32 + kg]);
            o[n] = __builtin_amdgcn_mfma_f32_16x16x32_bf16(ap, bv8, o[n], 0, 0, 0);
        }
    }

#pragma unroll
    for (int n = 0; n < 2; ++n)
#pragma unroll
        for (int r = 0; r < 4; ++r) {
            const int grow = wv * 16 + rowg + r;
            size_t oidx = vbase + (size_t)grow * vstride + n * 16 + rsel;
            float val = o[n][r];
            if (AXIS == 1) val += bf2f(addin[oidx]);
            outp[oidx] = f2bf(val);
        }
}

// ---------------------------------------------------------------------------
// Kernel 5: output MFMA GEMM, BK=64 (reg-staged): y16 @ Wot16^T + bo -> fp32
// 1D grid: yb = bid%2, mb = bid/2.
// ---------------------------------------------------------------------------
__global__ __launch_bounds__(256) void gemm_out_mfma(
    const unsigned short* __restrict__ y16, const unsigned short* __restrict__ Wot16,
    const float* __restrict__ bo, float* __restrict__ out)
{
    __shared__ __align__(16) unsigned short As[2][128 * 32];
    __shared__ __align__(16) unsigned short Bs[2][128 * 32];

    const int t = threadIdx.x;
    const int lane = t & 63, wid = t >> 6;
    const int wr = wid >> 1, wc = wid & 1;
    const int bid = blockIdx.x;
    const int m0 = (bid >> 1) * 128;
    const int n0 = (bid & 1) * 128;

    f32x4 acc[4][4];
#pragma unroll
    for (int i = 0; i < 4; ++i)
#pragma unroll
        for (int j = 0; j < 4; ++j)
#pragma unroll
            for (int q = 0; q < 4; ++q) acc[i][j][q] = 0.f;

    const int row_s = t >> 2;
    const int kp_s  = (t & 3) << 3;

    for (int ks = 0; ks < 4; ++ks) {
        const int k0 = ks * 64;
        uint4 a[2][2], b2[2][2];
#pragma unroll
        for (int h2 = 0; h2 < 2; ++h2) {
            const unsigned short* ap = y16 + (size_t)(m0 + row_s) * 256 + k0 + h2 * 32 + kp_s;
            a[h2][0] = *(const uint4*)ap;
            a[h2][1] = *(const uint4*)(ap + 64 * 256);
            const unsigned short* bp = Wot16 + (size_t)(n0 + row_s) * 256 + k0 + h2 * 32 + kp_s;
            b2[h2][0] = *(const uint4*)bp;
            b2[h2][1] = *(const uint4*)(bp + 64 * 256);
        }

        __syncthreads();
#pragma unroll
        for (int h2 = 0; h2 < 2; ++h2) {
            *(uint4*)(&As[h2][swz(row_s,      kp_s)]) = a[h2][0];
            *(uint4*)(&As[h2][swz(row_s + 64, kp_s)]) = a[h2][1];
            *(uint4*)(&Bs[h2][swz(row_s,      kp_s)]) = b2[h2][0];
            *(uint4*)(&Bs[h2][swz(row_s + 64, kp_s)]) = b2[h2][1];
        }
        __syncthreads();

        const int rsel = lane & 15, kg8 = (lane >> 4) << 3;
#pragma unroll
        for (int h2 = 0; h2 < 2; ++h2) {
            bf16x8 af[4], bf[4];
#pragma unroll
            for (int i = 0; i < 4; ++i)
                af[i] = *(const bf16x8*)(&As[h2][swz(wr * 64 + i * 16 + rsel, kg8)]);
#pragma unroll
            for (int j = 0; j < 4; ++j)
                bf[j] = *(const bf16x8*)(&Bs[h2][swz(wc * 64 + j * 16 + rsel, kg8)]);
#pragma unroll
            for (int i = 0; i < 4; ++i)
#pragma unroll
                for (int j = 0; j < 4; ++j)
                    acc[i][j] = __builtin_amdgcn_mfma_f32_16x16x32_bf16(af[i], bf[j], acc[i][j], 0, 0, 0);
        }
    }

    const int col_l = lane & 15, rowg = (lane >> 4) << 2;
#pragma unroll
    for (int i = 0; i < 4; ++i)
#pragma unroll
        for (int j = 0; j < 4; ++j) {
            int nn = n0 + wc * 64 + j * 16 + col_l;
            float bias = bo[nn];
#pragma unroll
            for (int r = 0; r < 4; ++r) {
                int m = m0 + wr * 64 + i * 16 + rowg + r;
                out[(size_t)m * 256 + nn] = acc[i][j][r] + bias;
            }
        }
}

// ---------------------------------------------------------------------------
extern "C" void kernel_launch(void* const* d_in, const int* in_sizes, int n_in,
                              void* d_out, int out_size, void* d_ws, size_t ws_size,
                              hipStream_t stream) {
    const float* x      = (const float*)d_in[0];
    const float* sin_t  = (const float*)d_in[1];
    const float* cos_t  = (const float*)d_in[2];
    const float* mask_h = (const float*)d_in[3];
    const float* mask_w = (const float*)d_in[4];
    const float* Wq     = (const float*)d_in[5];
    const float* bq     = (const float*)d_in[6];
    const float* Wk     = (const float*)d_in[7];
    const float* bk     = (const float*)d_in[8];
    const float* Wv     = (const float*)d_in[9];
    const float* bv     = (const float*)d_in[10];
    const float* conv_w = (const float*)d_in[11];
    const float* conv_b = (const float*)d_in[12];
    const float* Wo     = (const float*)d_in[13];
    const float* bo     = (const float*)d_in[14];

    // ws (bf16 buffers)
    unsigned short* ws    = (unsigned short*)d_ws;
    unsigned short* v16   = ws;              // (B,H,W,C)
    unsigned short* lepe16= v16 + NEL;       // (B,H,W,C)
    unsigned short* qr16  = lepe16 + NEL;    // (B,NH,H,W,KD)
    unsigned short* kr16  = qr16 + NEL;
    unsigned short* y16   = kr16 + NEL;      // (B,H,W,C)
    unsigned short* Wt16  = y16 + NEL;       // (768,256) n-major
    unsigned short* Wot16 = Wt16 + 768 * 256;// (256,256) n-major

    // d_out scratch: lower half = vv16 (bf16), upper half = x16 (bf16).
    unsigned short* vv16 = (unsigned short*)d_out;
    unsigned short* x16  = (unsigned short*)d_out + NEL;

    prep_x16<<<(int)(NEL / 2048), 256, 0, stream>>>(x, x16);
    trans_w<<<32, 256, 0, stream>>>(Wq, Wt16);
    trans_w<<<32, 256, 0, stream>>>(Wk, Wt16 + 256 * 256);
    trans_w<<<32, 256, 0, stream>>>(Wv, Wt16 + 512 * 256);
    trans_w<<<32, 256, 0, stream>>>(Wo, Wot16);

    qkv_mfma<<<(M_TOT / 128) * 6, 256, 0, stream>>>(
        x16, Wt16, bq, bk, bv, sin_t, cos_t, qr16, kr16, v16);

    conv_kernel<<<(int)(NEL / 32 / 256), 256, 0, stream>>>(v16, conv_w, conv_b, lepe16);

    attn_mfma<0><<<B * H * NH, 256, 0, stream>>>(qr16, kr16, v16, mask_w, nullptr, vv16);

    attn_mfma<1><<<B * W * NH, 256, 0, stream>>>(qr16, kr16, vv16, mask_h, lepe16, y16);

    gemm_out_mfma<<<(M_TOT / 128) * 2, 256, 0, stream>>>(y16, Wot16, bo, (float*)d_out);
}

// Round 16
// 256.323 us; speedup vs baseline: 1.4528x; 1.4528x over previous
//
#include <hip/hip_runtime.h>

typedef __attribute__((ext_vector_type(8))) short bf16x8;
typedef __attribute__((ext_vector_type(4))) float f32x4;

constexpr int B  = 16;
constexpr int H  = 64;
constexpr int W  = 64;
constexpr int C  = 256;
constexpr int NH = 8;
constexpr int KD = 32;
constexpr float SCALE = 0.17677669529663687f; // 32^-0.5
constexpr int M_TOT = B * H * W;              // 65536
constexpr size_t NEL = (size_t)B * H * W * C; // 16777216

__device__ __forceinline__ unsigned short f2bf(float f) {
    union { float f; unsigned int u; } x; x.f = f;
    unsigned int u = x.u;
    unsigned int r = (u + 0x7fffu + ((u >> 16) & 1u)) >> 16;
    return (unsigned short)r;
}
__device__ __forceinline__ float bf2f(unsigned short s) {
    union { unsigned int u; float f; } x; x.u = ((unsigned int)s) << 16; return x.f;
}
__device__ __forceinline__ float bf_lo(unsigned int u) {
    union { unsigned int u; float f; } x; x.u = u << 16; return x.f;
}
__device__ __forceinline__ float bf_hi(unsigned int u) {
    union { unsigned int u; float f; } x; x.u = u & 0xffff0000u; return x.f;
}
__device__ __forceinline__ unsigned int pack2(float a, float b) {
    return (unsigned int)f2bf(a) | ((unsigned int)f2bf(b) << 16);
}
__device__ __forceinline__ void cvt8(uint4 rv, float* f) {
    f[0] = bf_lo(rv.x); f[1] = bf_hi(rv.x); f[2] = bf_lo(rv.y); f[3] = bf_hi(rv.y);
    f[4] = bf_lo(rv.z); f[5] = bf_hi(rv.z); f[6] = bf_lo(rv.w); f[7] = bf_hi(rv.w);
}
// LDS chunk swizzle (write-side + read-side, value-consistent)
__device__ __forceinline__ int swz(int row, int kp8) {
    return row * 32 + (kp8 ^ (((row >> 2) & 3) << 3));
}

// ---------------------------------------------------------------------------
// prep: all 4 weight matrices (256k x 256n fp32) -> bf16 n-major, contiguous
// dst. mat = tidg>>13 (0=Wq,1=Wk,2=Wv,3=Wo). 128 blocks.
// ---------------------------------------------------------------------------
__global__ __launch_bounds__(256) void trans_all(
    const float* __restrict__ Wq, const float* __restrict__ Wk,
    const float* __restrict__ Wv, const float* __restrict__ Wo,
    unsigned short* __restrict__ dst) {
    int tidg = blockIdx.x * 256 + threadIdx.x;   // 0..32767
    int mat = tidg >> 13;
    int lt  = tidg & 8191;
    int n = lt >> 5, k0 = (lt & 31) << 3;
    const float* __restrict__ src = (mat == 0) ? Wq : (mat == 1) ? Wk : (mat == 2) ? Wv : Wo;
    unsigned int p[4];
#pragma unroll
    for (int j = 0; j < 4; ++j) {
        float a  = src[(size_t)(k0 + 2 * j) * 256 + n];
        float b2 = src[(size_t)(k0 + 2 * j + 1) * 256 + n];
        p[j] = pack2(a, b2);
    }
    uint4 o = {p[0], p[1], p[2], p[3]};
    *(uint4*)(dst + ((size_t)mat * 65536) + (size_t)n * 256 + k0) = o;
}

// ---------------------------------------------------------------------------
// Kernel 1: fused QKV MFMA GEMM (reg-staged LDS, R12 structure; reads fp32 x
// and converts during staging -> prep_x16 eliminated).
// Swapped MFMA: C[row->n][col->m]. y 0..3 = q,k halves; y 4..5 = v.
// ---------------------------------------------------------------------------
__global__ __launch_bounds__(256) void qkv_mfma(
    const float* __restrict__ x, const unsigned short* __restrict__ Wt16,
    const float* __restrict__ bq, const float* __restrict__ bk, const float* __restrict__ bv,
    const float* __restrict__ sin_t, const float* __restrict__ cos_t,
    unsigned short* __restrict__ qr, unsigned short* __restrict__ kr,
    unsigned short* __restrict__ v16)
{
    __shared__ __align__(16) unsigned short As[128 * 32];
    __shared__ __align__(16) unsigned short Bs[128 * 32];

    const int t = threadIdx.x;
    const int lane = t & 63, wid = t >> 6;
    const int wr = wid >> 1, wc = wid & 1;
    const int m0 = blockIdx.x * 128;
    const int n0 = blockIdx.y * 128;          // Wt16 row base (0..640)
    const int matid = blockIdx.y >> 1;        // 0=q 1=k 2=v
    const int nb = n0 & 255;                  // within-matrix n base

    f32x4 acc[4][4];
#pragma unroll
    for (int i = 0; i < 4; ++i)
#pragma unroll
        for (int j = 0; j < 4; ++j)
#pragma unroll
            for (int q = 0; q < 4; ++q) acc[i][j][q] = 0.f;

    const int row_s = t >> 2;            // 0..63
    const int kp_s  = (t & 3) << 3;      // 0,8,16,24

    for (int ks = 0; ks < 8; ++ks) {
        const int k0 = ks * 32;
        // A: fp32 x, convert in-register
        const float* ap = x + (size_t)(m0 + row_s) * 256 + k0 + kp_s;
        float4 f00 = *(const float4*)ap;
        float4 f01 = *(const float4*)(ap + 4);
        float4 f10 = *(const float4*)(ap + 64 * 256);
        float4 f11 = *(const float4*)(ap + 64 * 256 + 4);
        uint4 a0 = {pack2(f00.x, f00.y), pack2(f00.z, f00.w),
                    pack2(f01.x, f01.y), pack2(f01.z, f01.w)};
        uint4 a1 = {pack2(f10.x, f10.y), pack2(f10.z, f10.w),
                    pack2(f11.x, f11.y), pack2(f11.z, f11.w)};
        // B: bf16 weights
        const unsigned short* bp = Wt16 + (size_t)(n0 + row_s) * 256 + k0 + kp_s;
        uint4 b0 = *(const uint4*)bp;
        uint4 b1 = *(const uint4*)(bp + 64 * 256);

        __syncthreads();
        *(uint4*)(&As[swz(row_s,      kp_s)]) = a0;
        *(uint4*)(&As[swz(row_s + 64, kp_s)]) = a1;
        *(uint4*)(&Bs[swz(row_s,      kp_s)]) = b0;
        *(uint4*)(&Bs[swz(row_s + 64, kp_s)]) = b1;
        __syncthreads();

        bf16x8 af[4], bf[4];
        const int rsel = lane & 15, kg8 = (lane >> 4) << 3;
#pragma unroll
        for (int i = 0; i < 4; ++i)
            af[i] = *(const bf16x8*)(&As[swz(wr * 64 + i * 16 + rsel, kg8)]);
#pragma unroll
        for (int j = 0; j < 4; ++j)
            bf[j] = *(const bf16x8*)(&Bs[swz(wc * 64 + j * 16 + rsel, kg8)]);
        // swapped: C[row->n][col->m]
#pragma unroll
        for (int i = 0; i < 4; ++i)
#pragma unroll
            for (int j = 0; j < 4; ++j)
                acc[i][j] = __builtin_amdgcn_mfma_f32_16x16x32_bf16(bf[j], af[i], acc[i][j], 0, 0, 0);
    }

    const int col_l = lane & 15, rowg = (lane >> 4) << 2;
    if (matid == 2) {
        // v: lane holds 4 consecutive n at row m -> ushort4 store
#pragma unroll
        for (int i = 0; i < 4; ++i) {
            const int m = m0 + wr * 64 + i * 16 + col_l;
#pragma unroll
            for (int j = 0; j < 4; ++j) {
                const int nn = nb + wc * 64 + j * 16 + rowg;
                float4 bias4 = *(const float4*)(bv + nn);
                ushort4 o;
                o.x = f2bf(acc[i][j][0] + bias4.x);
                o.y = f2bf(acc[i][j][1] + bias4.y);
                o.z = f2bf(acc[i][j][2] + bias4.z);
                o.w = f2bf(acc[i][j][3] + bias4.w);
                *(ushort4*)(v16 + (size_t)m * 256 + nn) = o;
            }
        }
    } else {
        // q/k: lane holds 4 consecutive d -> in-lane rotary, 8B stores
        const float sc = matid ? SCALE : 1.0f;
        const float* __restrict__ bias = matid ? bk : bq;
        unsigned short* __restrict__ dst = matid ? kr : qr;
#pragma unroll
        for (int i = 0; i < 4; ++i) {
            const int m = m0 + wr * 64 + i * 16 + col_l;
            const int bb = m >> 12, hh = (m >> 6) & 63, ww = m & 63;
            const size_t pixbase = ((size_t)hh * 64 + ww) * 32;
#pragma unroll
            for (int j = 0; j < 4; ++j) {
                const int n = nb + wc * 64 + j * 16 + rowg;  // 4 consecutive n
                const int nh = n >> 5, db = n & 31;
                float4 bias4 = *(const float4*)(bias + n);
                float4 cs4 = *(const float4*)(cos_t + pixbase + db);
                float4 sn4 = *(const float4*)(sin_t + pixbase + db);
                float v0 = (acc[i][j][0] + bias4.x) * sc;
                float v1 = (acc[i][j][1] + bias4.y) * sc;
                float v2 = (acc[i][j][2] + bias4.z) * sc;
                float v3 = (acc[i][j][3] + bias4.w) * sc;
                ushort4 o;
                o.x = f2bf(v0 * cs4.x - v1 * sn4.x);
                o.y = f2bf(v1 * cs4.y + v0 * sn4.y);
                o.z = f2bf(v2 * cs4.z - v3 * sn4.z);
                o.w = f2bf(v3 * cs4.w + v2 * sn4.w);
                *(ushort4*)(dst + ((((size_t)bb * 8 + nh) * 64 + hh) * 64 + ww) * 32 + db) = o;
            }
        }
    }
}

// ---------------------------------------------------------------------------
// Kernel 2: 5x5 depthwise conv (lepe), bf16 in/out.
// Each thread: 8 channels x 4 consecutive w. Row-register reuse across taps.
// ---------------------------------------------------------------------------
__global__ __launch_bounds__(256) void conv_kernel(
    const unsigned short* __restrict__ v, const float* __restrict__ cw,
    const float* __restrict__ cb, unsigned short* __restrict__ lepe)
{
    size_t tid = (size_t)blockIdx.x * 256 + threadIdx.x;   // 512K threads
    const int c8 = (int)(tid & 31) << 3;          // channel group of 8
    const int w0 = ((int)(tid >> 5) & 15) << 2;   // 0,4,..,60
    const int h  = (int)(tid >> 9) & 63;
    const int b  = (int)(tid >> 15);

    float acc[4][8];
    {
        float4 cb0 = *(const float4*)(cb + c8);
        float4 cb1 = *(const float4*)(cb + c8 + 4);
#pragma unroll
        for (int o = 0; o < 4; ++o) {
            acc[o][0] = cb0.x; acc[o][1] = cb0.y; acc[o][2] = cb0.z; acc[o][3] = cb0.w;
            acc[o][4] = cb1.x; acc[o][5] = cb1.y; acc[o][6] = cb1.z; acc[o][7] = cb1.w;
        }
    }

    const unsigned short* __restrict__ vb = v + (size_t)b * 4096 * 256 + c8;
#pragma unroll
    for (int dy = 0; dy < 5; ++dy) {
        const int yy = h + dy - 2;
        if (yy < 0 || yy >= 64) continue;
        float rowf[8][8];
#pragma unroll
        for (int j = 0; j < 8; ++j) {
            const int xx = w0 + j - 2;
            if (xx < 0 || xx >= 64) {
#pragma unroll
                for (int q = 0; q < 8; ++q) rowf[j][q] = 0.f;
            } else {
                uint4 rv = *(const uint4*)(vb + (size_t)(yy * 64 + xx) * 256);
                cvt8(rv, rowf[j]);
            }
        }
#pragma unroll
        for (int dx = 0; dx < 5; ++dx) {
            const float* wp = cw + (dy * 5 + dx) * 256 + c8;
            float4 wv0 = *(const float4*)wp;
            float4 wv1 = *(const float4*)(wp + 4);
#pragma unroll
            for (int o = 0; o < 4; ++o) {
                const float* rf = rowf[dx + o];
                acc[o][0] += rf[0] * wv0.x; acc[o][1] += rf[1] * wv0.y;
                acc[o][2] += rf[2] * wv0.z; acc[o][3] += rf[3] * wv0.w;
                acc[o][4] += rf[4] * wv1.x; acc[o][5] += rf[5] * wv1.y;
                acc[o][6] += rf[6] * wv1.z; acc[o][7] += rf[7] * wv1.w;
            }
        }
    }

    unsigned short* __restrict__ op = lepe + (((size_t)(b * 64 + h) * 64) + w0) * 256 + c8;
#pragma unroll
    for (int o = 0; o < 4; ++o) {
        uint4 ov;
        ov.x = pack2(acc[o][0], acc[o][1]); ov.y = pack2(acc[o][2], acc[o][3]);
        ov.z = pack2(acc[o][4], acc[o][5]); ov.w = pack2(acc[o][6], acc[o][7]);
        *(uint4*)(op + (size_t)o * 256) = ov;
    }
}

// ---------------------------------------------------------------------------
// Kernel 3/4: MFMA attention along one axis. One block per (b,pos,nh).
// ---------------------------------------------------------------------------
template <int AXIS>
__global__ __launch_bounds__(256) void attn_mfma(
    const unsigned short* __restrict__ qr, const unsigned short* __restrict__ kr,
    const unsigned short* __restrict__ vin, const float* __restrict__ mask,
    const unsigned short* __restrict__ addin, unsigned short* __restrict__ outp)
{
    __shared__ __align__(16) short qs[64 * 40];
    __shared__ __align__(16) short ks[64 * 40];
    __shared__ __align__(16) short vt[32 * 72];
    __shared__ __align__(16) short P [64 * 72];

    const int t    = threadIdx.x;
    const int lane = t & 63, wv = t >> 6;
    const int bid  = blockIdx.x;
    const int nh   = bid & 7;
    const int pos  = (bid >> 3) & 63;
    const int b    = bid >> 9;

    size_t qbase, vbase;
    int qstride, vstride;
    if (AXIS == 0) {
        qbase   = ((size_t)(b * 8 + nh) * 64 + pos) * 2048;
        qstride = 32;
        vbase   = ((size_t)(b * 64 + pos) * 64) * 256 + nh * 32;
        vstride = 256;
    } else {
        qbase   = ((size_t)(b * 8 + nh) * 64) * 2048 + pos * 32;
        qstride = 2048;
        vbase   = ((size_t)b * 64 * 64) * 256 + pos * 256 + nh * 32;
        vstride = 16384;
    }

    {
        int row = t >> 2, c8 = (t & 3) << 3;
        uint4 rq = *(const uint4*)(qr + qbase + (size_t)row * qstride + c8);
        *(uint4*)(&qs[row * 40 + c8]) = rq;
        uint4 rk = *(const uint4*)(kr + qbase + (size_t)row * qstride + c8);
        *(uint4*)(&ks[row * 40 + c8]) = rk;
        uint4 rv = *(const uint4*)(vin + vbase + (size_t)row * vstride + c8);
        const unsigned short* pv = (const unsigned short*)&rv;
#pragma unroll
        for (int j = 0; j < 8; ++j) vt[(c8 + j) * 72 + row] = pv[j];
    }
    __syncthreads();

    const int rsel = lane & 15;
    const int kg   = (lane >> 4) << 3;
    const int rowg = (lane >> 4) << 2;

    bf16x8 aq = *(const bf16x8*)(&qs[(wv * 16 + rsel) * 40 + kg]);
    f32x4 s[4];
#pragma unroll
    for (int j = 0; j < 4; ++j) {
        f32x4 z = {0.f, 0.f, 0.f, 0.f};
        bf16x8 bk8 = *(const bf16x8*)(&ks[(j * 16 + rsel) * 40 + kg]);
        s[j] = __builtin_amdgcn_mfma_f32_16x16x32_bf16(aq, bk8, z, 0, 0, 0);
    }

    const float* __restrict__ mrow = mask + (size_t)nh * 4096;
#pragma unroll
    for (int r = 0; r < 4; ++r) {
        const int grow = wv * 16 + rowg + r;
#pragma unroll
        for (int j = 0; j < 4; ++j)
            s[j][r] += mrow[grow * 64 + j * 16 + rsel];
        float mx = fmaxf(fmaxf(s[0][r], s[1][r]), fmaxf(s[2][r], s[3][r]));
        mx = fmaxf(mx, __shfl_xor(mx, 1));
        mx = fmaxf(mx, __shfl_xor(mx, 2));
        mx = fmaxf(mx, __shfl_xor(mx, 4));
        mx = fmaxf(mx, __shfl_xor(mx, 8));
        float e0 = __expf(s[0][r] - mx), e1 = __expf(s[1][r] - mx);
        float e2 = __expf(s[2][r] - mx), e3 = __expf(s[3][r] - mx);
        float sum = e0 + e1 + e2 + e3;
        sum += __shfl_xor(sum, 1);
        sum += __shfl_xor(sum, 2);
        sum += __shfl_xor(sum, 4);
        sum += __shfl_xor(sum, 8);
        float inv = 1.0f / sum;
        P[grow * 72 +      rsel] = f2bf(e0 * inv);
        P[grow * 72 + 16 + rsel] = f2bf(e1 * inv);
        P[grow * 72 + 32 + rsel] = f2bf(e2 * inv);
        P[grow * 72 + 48 + rsel] = f2bf(e3 * inv);
    }
    __syncthreads();

    f32x4 o[2];
#pragma unroll
    for (int n = 0; n < 2; ++n)
#pragma unroll
        for (int q = 0; q < 4; ++q) o[n][q] = 0.f;
#pragma unroll
    for (int kk = 0; kk < 2; ++kk) {
        bf16x8 ap = *(const bf16x8*)(&P[(wv * 16 + rsel) * 72 + kk * 32 + kg]);
#pragma unroll
        for (int n = 0; n < 2; ++n) {
            bf16x8 bv8 = *(const bf16x8*)(&vt[(n * 16 + rsel) * 72 + kk * 32 + kg]);
            o[n] = __builtin_amdgcn_mfma_f32_16x16x32_bf16(ap, bv8, o[n], 0, 0, 0);
        }
    }

#pragma unroll
    for (int n = 0; n < 2; ++n)
#pragma unroll
        for (int r = 0; r < 4; ++r) {
            const int grow = wv * 16 + rowg + r;
            size_t oidx = vbase + (size_t)grow * vstride + n * 16 + rsel;
            float val = o[n][r];
            if (AXIS == 1) val += bf2f(addin[oidx]);
            outp[oidx] = f2bf(val);
        }
}

// ---------------------------------------------------------------------------
// Kernel 5: output MFMA GEMM (reg-staged, R12 structure): y16 @ Wot16^T + bo
// ---------------------------------------------------------------------------
__global__ __launch_bounds__(256) void gemm_out_mfma(
    const unsigned short* __restrict__ y16, const unsigned short* __restrict__ Wot16,
    const float* __restrict__ bo, float* __restrict__ out)
{
    __shared__ __align__(16) unsigned short As[128 * 32];
    __shared__ __align__(16) unsigned short Bs[128 * 32];

    const int t = threadIdx.x;
    const int lane = t & 63, wid = t >> 6;
    const int wr = wid >> 1, wc = wid & 1;
    const int m0 = blockIdx.x * 128;
    const int n0 = blockIdx.y * 128;

    f32x4 acc[4][4];
#pragma unroll
    for (int i = 0; i < 4; ++i)
#pragma unroll
        for (int j = 0; j < 4; ++j)
#pragma unroll
            for (int q = 0; q < 4; ++q) acc[i][j][q] = 0.f;

    const int row_s = t >> 2;
    const int kp_s  = (t & 3) << 3;

    for (int ks = 0; ks < 8; ++ks) {
        const int k0 = ks * 32;
        const unsigned short* ap = y16 + (size_t)(m0 + row_s) * 256 + k0 + kp_s;
        uint4 a0 = *(const uint4*)ap;
        uint4 a1 = *(const uint4*)(ap + 64 * 256);
        const unsigned short* bp = Wot16 + (size_t)(n0 + row_s) * 256 + k0 + kp_s;
        uint4 b0 = *(const uint4*)bp;
        uint4 b1 = *(const uint4*)(bp + 64 * 256);

        __syncthreads();
        *(uint4*)(&As[swz(row_s,      kp_s)]) = a0;
        *(uint4*)(&As[swz(row_s + 64, kp_s)]) = a1;
        *(uint4*)(&Bs[swz(row_s,      kp_s)]) = b0;
        *(uint4*)(&Bs[swz(row_s + 64, kp_s)]) = b1;
        __syncthreads();

        bf16x8 af[4], bf[4];
        const int rsel = lane & 15, kg8 = (lane >> 4) << 3;
#pragma unroll
        for (int i = 0; i < 4; ++i)
            af[i] = *(const bf16x8*)(&As[swz(wr * 64 + i * 16 + rsel, kg8)]);
#pragma unroll
        for (int j = 0; j < 4; ++j)
            bf[j] = *(const bf16x8*)(&Bs[swz(wc * 64 + j * 16 + rsel, kg8)]);
#pragma unroll
        for (int i = 0; i < 4; ++i)
#pragma unroll
            for (int j = 0; j < 4; ++j)
                acc[i][j] = __builtin_amdgcn_mfma_f32_16x16x32_bf16(af[i], bf[j], acc[i][j], 0, 0, 0);
    }

    const int col_l = lane & 15, rowg = (lane >> 4) << 2;
#pragma unroll
    for (int i = 0; i < 4; ++i)
#pragma unroll
        for (int j = 0; j < 4; ++j) {
            int nn = n0 + wc * 64 + j * 16 + col_l;
            float bias = bo[nn];
#pragma unroll
            for (int r = 0; r < 4; ++r) {
                int m = m0 + wr * 64 + i * 16 + rowg + r;
                out[(size_t)m * 256 + nn] = acc[i][j][r] + bias;
            }
        }
}

// ---------------------------------------------------------------------------
extern "C" void kernel_launch(void* const* d_in, const int* in_sizes, int n_in,
                              void* d_out, int out_size, void* d_ws, size_t ws_size,
                              hipStream_t stream) {
    const float* x      = (const float*)d_in[0];
    const float* sin_t  = (const float*)d_in[1];
    const float* cos_t  = (const float*)d_in[2];
    const float* mask_h = (const float*)d_in[3];
    const float* mask_w = (const float*)d_in[4];
    const float* Wq     = (const float*)d_in[5];
    const float* bq     = (const float*)d_in[6];
    const float* Wk     = (const float*)d_in[7];
    const float* bk     = (const float*)d_in[8];
    const float* Wv     = (const float*)d_in[9];
    const float* bv     = (const float*)d_in[10];
    const float* conv_w = (const float*)d_in[11];
    const float* conv_b = (const float*)d_in[12];
    const float* Wo     = (const float*)d_in[13];
    const float* bo     = (const float*)d_in[14];

    // ws (bf16 buffers)
    unsigned short* ws    = (unsigned short*)d_ws;
    unsigned short* v16   = ws;              // (B,H,W,C)
    unsigned short* lepe16= v16 + NEL;       // (B,H,W,C)
    unsigned short* qr16  = lepe16 + NEL;    // (B,NH,H,W,KD)
    unsigned short* kr16  = qr16 + NEL;
    unsigned short* y16   = kr16 + NEL;      // (B,H,W,C)
    unsigned short* Wt16  = y16 + NEL;       // (768,256) n-major (+Wo after)
    unsigned short* Wot16 = Wt16 + 768 * 256;// (256,256) n-major

    // d_out scratch: lower half = vv16 (bf16)
    unsigned short* vv16 = (unsigned short*)d_out;

    trans_all<<<128, 256, 0, stream>>>(Wq, Wk, Wv, Wo, Wt16);

    qkv_mfma<<<dim3(M_TOT / 128, 6), 256, 0, stream>>>(
        x, Wt16, bq, bk, bv, sin_t, cos_t, qr16, kr16, v16);

    conv_kernel<<<(int)(NEL / 32 / 256), 256, 0, stream>>>(v16, conv_w, conv_b, lepe16);

    attn_mfma<0><<<B * H * NH, 256, 0, stream>>>(qr16, kr16, v16, mask_w, nullptr, vv16);

    attn_mfma<1><<<B * W * NH, 256, 0, stream>>>(qr16, kr16, vv16, mask_h, lepe16, y16);

    gemm_out_mfma<<<dim3(M_TOT / 128, 2), 256, 0, stream>>>(y16, Wot16, bo, (float*)d_out);
}

// Round 17
// 240.287 us; speedup vs baseline: 1.5498x; 1.0667x over previous
//
#include <hip/hip_runtime.h>

typedef __attribute__((ext_vector_type(8))) short bf16x8;
typedef __attribute__((ext_vector_type(4))) float f32x4;

constexpr int B  = 16;
constexpr int H  = 64;
constexpr int W  = 64;
constexpr int C  = 256;
constexpr int NH = 8;
constexpr int KD = 32;
constexpr float SCALE = 0.17677669529663687f; // 32^-0.5
constexpr int M_TOT = B * H * W;              // 65536
constexpr size_t NEL = (size_t)B * H * W * C; // 16777216

__device__ __forceinline__ unsigned short f2bf(float f) {
    union { float f; unsigned int u; } x; x.f = f;
    unsigned int u = x.u;
    unsigned int r = (u + 0x7fffu + ((u >> 16) & 1u)) >> 16;
    return (unsigned short)r;
}
__device__ __forceinline__ float bf2f(unsigned short s) {
    union { unsigned int u; float f; } x; x.u = ((unsigned int)s) << 16; return x.f;
}
__device__ __forceinline__ float bf_lo(unsigned int u) {
    union { unsigned int u; float f; } x; x.u = u << 16; return x.f;
}
__device__ __forceinline__ float bf_hi(unsigned int u) {
    union { unsigned int u; float f; } x; x.u = u & 0xffff0000u; return x.f;
}
__device__ __forceinline__ unsigned int pack2(float a, float b) {
    return (unsigned int)f2bf(a) | ((unsigned int)f2bf(b) << 16);
}
__device__ __forceinline__ void cvt8(uint4 rv, float* f) {
    f[0] = bf_lo(rv.x); f[1] = bf_hi(rv.x); f[2] = bf_lo(rv.y); f[3] = bf_hi(rv.y);
    f[4] = bf_lo(rv.z); f[5] = bf_hi(rv.z); f[6] = bf_lo(rv.w); f[7] = bf_hi(rv.w);
}
// LDS chunk swizzle (write-side + read-side, value-consistent)
__device__ __forceinline__ int swz(int row, int kp8) {
    return row * 32 + (kp8 ^ (((row >> 2) & 3) << 3));
}

// ---------------------------------------------------------------------------
// prep: x fp32 -> bf16
// ---------------------------------------------------------------------------
__global__ __launch_bounds__(256) void prep_x16(const float* __restrict__ x,
                                                unsigned short* __restrict__ x16) {
    size_t i8 = ((size_t)blockIdx.x * 256 + threadIdx.x) * 8;
    float4 f0 = *(const float4*)(x + i8);
    float4 f1 = *(const float4*)(x + i8 + 4);
    uint4 o;
    o.x = pack2(f0.x, f0.y); o.y = pack2(f0.z, f0.w);
    o.z = pack2(f1.x, f1.y); o.w = pack2(f1.z, f1.w);
    *(uint4*)(x16 + i8) = o;
}

// ---------------------------------------------------------------------------
// prep: all 4 weight matrices (256k x 256n fp32) -> bf16 n-major, contiguous
// dst. mat = tidg>>13 (0=Wq,1=Wk,2=Wv,3=Wo). 128 blocks.
// ---------------------------------------------------------------------------
__global__ __launch_bounds__(256) void trans_all(
    const float* __restrict__ Wq, const float* __restrict__ Wk,
    const float* __restrict__ Wv, const float* __restrict__ Wo,
    unsigned short* __restrict__ dst) {
    int tidg = blockIdx.x * 256 + threadIdx.x;   // 0..32767
    int mat = tidg >> 13;
    int lt  = tidg & 8191;
    int n = lt >> 5, k0 = (lt & 31) << 3;
    const float* __restrict__ src = (mat == 0) ? Wq : (mat == 1) ? Wk : (mat == 2) ? Wv : Wo;
    unsigned int p[4];
#pragma unroll
    for (int j = 0; j < 4; ++j) {
        float a  = src[(size_t)(k0 + 2 * j) * 256 + n];
        float b2 = src[(size_t)(k0 + 2 * j + 1) * 256 + n];
        p[j] = pack2(a, b2);
    }
    uint4 o = {p[0], p[1], p[2], p[3]};
    *(uint4*)(dst + ((size_t)mat * 65536) + (size_t)n * 256 + k0) = o;
}

// ---------------------------------------------------------------------------
// Kernel 1: fused QKV MFMA GEMM (reg-staged LDS, R12 structure, bf16 x16 in).
// Swapped MFMA: C[row->n][col->m]. y 0..3 = q,k halves; y 4..5 = v.
// ---------------------------------------------------------------------------
__global__ __launch_bounds__(256) void qkv_mfma(
    const unsigned short* __restrict__ x16, const unsigned short* __restrict__ Wt16,
    const float* __restrict__ bq, const float* __restrict__ bk, const float* __restrict__ bv,
    const float* __restrict__ sin_t, const float* __restrict__ cos_t,
    unsigned short* __restrict__ qr, unsigned short* __restrict__ kr,
    unsigned short* __restrict__ v16)
{
    __shared__ __align__(16) unsigned short As[128 * 32];
    __shared__ __align__(16) unsigned short Bs[128 * 32];

    const int t = threadIdx.x;
    const int lane = t & 63, wid = t >> 6;
    const int wr = wid >> 1, wc = wid & 1;
    const int m0 = blockIdx.x * 128;
    const int n0 = blockIdx.y * 128;          // Wt16 row base (0..640)
    const int matid = blockIdx.y >> 1;        // 0=q 1=k 2=v
    const int nb = n0 & 255;                  // within-matrix n base

    f32x4 acc[4][4];
#pragma unroll
    for (int i = 0; i < 4; ++i)
#pragma unroll
        for (int j = 0; j < 4; ++j)
#pragma unroll
            for (int q = 0; q < 4; ++q) acc[i][j][q] = 0.f;

    const int row_s = t >> 2;            // 0..63
    const int kp_s  = (t & 3) << 3;      // 0,8,16,24

    for (int ks = 0; ks < 8; ++ks) {
        const int k0 = ks * 32;
        const unsigned short* ap = x16 + (size_t)(m0 + row_s) * 256 + k0 + kp_s;
        uint4 a0 = *(const uint4*)ap;
        uint4 a1 = *(const uint4*)(ap + 64 * 256);
        const unsigned short* bp = Wt16 + (size_t)(n0 + row_s) * 256 + k0 + kp_s;
        uint4 b0 = *(const uint4*)bp;
        uint4 b1 = *(const uint4*)(bp + 64 * 256);

        __syncthreads();
        *(uint4*)(&As[swz(row_s,      kp_s)]) = a0;
        *(uint4*)(&As[swz(row_s + 64, kp_s)]) = a1;
        *(uint4*)(&Bs[swz(row_s,      kp_s)]) = b0;
        *(uint4*)(&Bs[swz(row_s + 64, kp_s)]) = b1;
        __syncthreads();

        bf16x8 af[4], bf[4];
        const int rsel = lane & 15, kg8 = (lane >> 4) << 3;
#pragma unroll
        for (int i = 0; i < 4; ++i)
            af[i] = *(const bf16x8*)(&As[swz(wr * 64 + i * 16 + rsel, kg8)]);
#pragma unroll
        for (int j = 0; j < 4; ++j)
            bf[j] = *(const bf16x8*)(&Bs[swz(wc * 64 + j * 16 + rsel, kg8)]);
        // swapped: C[row->n][col->m]
#pragma unroll
        for (int i = 0; i < 4; ++i)
#pragma unroll
            for (int j = 0; j < 4; ++j)
                acc[i][j] = __builtin_amdgcn_mfma_f32_16x16x32_bf16(bf[j], af[i], acc[i][j], 0, 0, 0);
    }

    const int col_l = lane & 15, rowg = (lane >> 4) << 2;
    if (matid == 2) {
        // v: lane holds 4 consecutive n at row m -> ushort4 store
#pragma unroll
        for (int i = 0; i < 4; ++i) {
            const int m = m0 + wr * 64 + i * 16 + col_l;
#pragma unroll
            for (int j = 0; j < 4; ++j) {
                const int nn = nb + wc * 64 + j * 16 + rowg;
                float4 bias4 = *(const float4*)(bv + nn);
                ushort4 o;
                o.x = f2bf(acc[i][j][0] + bias4.x);
                o.y = f2bf(acc[i][j][1] + bias4.y);
                o.z = f2bf(acc[i][j][2] + bias4.z);
                o.w = f2bf(acc[i][j][3] + bias4.w);
                *(ushort4*)(v16 + (size_t)m * 256 + nn) = o;
            }
        }
    } else {
        // q/k: lane holds 4 consecutive d -> in-lane rotary, 8B stores
        const float sc = matid ? SCALE : 1.0f;
        const float* __restrict__ bias = matid ? bk : bq;
        unsigned short* __restrict__ dst = matid ? kr : qr;
#pragma unroll
        for (int i = 0; i < 4; ++i) {
            const int m = m0 + wr * 64 + i * 16 + col_l;
            const int bb = m >> 12, hh = (m >> 6) & 63, ww = m & 63;
            const size_t pixbase = ((size_t)hh * 64 + ww) * 32;
#pragma unroll
            for (int j = 0; j < 4; ++j) {
                const int n = nb + wc * 64 + j * 16 + rowg;  // 4 consecutive n
                const int nh = n >> 5, db = n & 31;
                float4 bias4 = *(const float4*)(bias + n);
                float4 cs4 = *(const float4*)(cos_t + pixbase + db);
                float4 sn4 = *(const float4*)(sin_t + pixbase + db);
                float v0 = (acc[i][j][0] + bias4.x) * sc;
                float v1 = (acc[i][j][1] + bias4.y) * sc;
                float v2 = (acc[i][j][2] + bias4.z) * sc;
                float v3 = (acc[i][j][3] + bias4.w) * sc;
                ushort4 o;
                o.x = f2bf(v0 * cs4.x - v1 * sn4.x);
                o.y = f2bf(v1 * cs4.y + v0 * sn4.y);
                o.z = f2bf(v2 * cs4.z - v3 * sn4.z);
                o.w = f2bf(v3 * cs4.w + v2 * sn4.w);
                *(ushort4*)(dst + ((((size_t)bb * 8 + nh) * 64 + hh) * 64 + ww) * 32 + db) = o;
            }
        }
    }
}

// ---------------------------------------------------------------------------
// Kernel 2: 5x5 depthwise conv (lepe), bf16 in/out.
// Each thread: 8 channels x 4 consecutive w. Row-register reuse across taps.
// ---------------------------------------------------------------------------
__global__ __launch_bounds__(256) void conv_kernel(
    const unsigned short* __restrict__ v, const float* __restrict__ cw,
    const float* __restrict__ cb, unsigned short* __restrict__ lepe)
{
    size_t tid = (size_t)blockIdx.x * 256 + threadIdx.x;   // 512K threads
    const int c8 = (int)(tid & 31) << 3;          // channel group of 8
    const int w0 = ((int)(tid >> 5) & 15) << 2;   // 0,4,..,60
    const int h  = (int)(tid >> 9) & 63;
    const int b  = (int)(tid >> 15);

    float acc[4][8];
    {
        float4 cb0 = *(const float4*)(cb + c8);
        float4 cb1 = *(const float4*)(cb + c8 + 4);
#pragma unroll
        for (int o = 0; o < 4; ++o) {
            acc[o][0] = cb0.x; acc[o][1] = cb0.y; acc[o][2] = cb0.z; acc[o][3] = cb0.w;
            acc[o][4] = cb1.x; acc[o][5] = cb1.y; acc[o][6] = cb1.z; acc[o][7] = cb1.w;
        }
    }

    const unsigned short* __restrict__ vb = v + (size_t)b * 4096 * 256 + c8;
#pragma unroll
    for (int dy = 0; dy < 5; ++dy) {
        const int yy = h + dy - 2;
        if (yy < 0 || yy >= 64) continue;
        float rowf[8][8];
#pragma unroll
        for (int j = 0; j < 8; ++j) {
            const int xx = w0 + j - 2;
            if (xx < 0 || xx >= 64) {
#pragma unroll
                for (int q = 0; q < 8; ++q) rowf[j][q] = 0.f;
            } else {
                uint4 rv = *(const uint4*)(vb + (size_t)(yy * 64 + xx) * 256);
                cvt8(rv, rowf[j]);
            }
        }
#pragma unroll
        for (int dx = 0; dx < 5; ++dx) {
            const float* wp = cw + (dy * 5 + dx) * 256 + c8;
            float4 wv0 = *(const float4*)wp;
            float4 wv1 = *(const float4*)(wp + 4);
#pragma unroll
            for (int o = 0; o < 4; ++o) {
                const float* rf = rowf[dx + o];
                acc[o][0] += rf[0] * wv0.x; acc[o][1] += rf[1] * wv0.y;
                acc[o][2] += rf[2] * wv0.z; acc[o][3] += rf[3] * wv0.w;
                acc[o][4] += rf[4] * wv1.x; acc[o][5] += rf[5] * wv1.y;
                acc[o][6] += rf[6] * wv1.z; acc[o][7] += rf[7] * wv1.w;
            }
        }
    }

    unsigned short* __restrict__ op = lepe + (((size_t)(b * 64 + h) * 64) + w0) * 256 + c8;
#pragma unroll
    for (int o = 0; o < 4; ++o) {
        uint4 ov;
        ov.x = pack2(acc[o][0], acc[o][1]); ov.y = pack2(acc[o][2], acc[o][3]);
        ov.z = pack2(acc[o][4], acc[o][5]); ov.w = pack2(acc[o][6], acc[o][7]);
        *(uint4*)(op + (size_t)o * 256) = ov;
    }
}

// ---------------------------------------------------------------------------
// Kernel 3/4: MFMA attention along one axis. One block per (b,pos,nh).
// ---------------------------------------------------------------------------
template <int AXIS>
__global__ __launch_bounds__(256) void attn_mfma(
    const unsigned short* __restrict__ qr, const unsigned short* __restrict__ kr,
    const unsigned short* __restrict__ vin, const float* __restrict__ mask,
    const unsigned short* __restrict__ addin, unsigned short* __restrict__ outp)
{
    __shared__ __align__(16) short qs[64 * 40];
    __shared__ __align__(16) short ks[64 * 40];
    __shared__ __align__(16) short vt[32 * 72];
    __shared__ __align__(16) short P [64 * 72];

    const int t    = threadIdx.x;
    const int lane = t & 63, wv = t >> 6;
    const int bid  = blockIdx.x;
    const int nh   = bid & 7;
    const int pos  = (bid >> 3) & 63;
    const int b    = bid >> 9;

    size_t qbase, vbase;
    int qstride, vstride;
    if (AXIS == 0) {
        qbase   = ((size_t)(b * 8 + nh) * 64 + pos) * 2048;
        qstride = 32;
        vbase   = ((size_t)(b * 64 + pos) * 64) * 256 + nh * 32;
        vstride = 256;
    } else {
        qbase   = ((size_t)(b * 8 + nh) * 64) * 2048 + pos * 32;
        qstride = 2048;
        vbase   = ((size_t)b * 64 * 64) * 256 + pos * 256 + nh * 32;
        vstride = 16384;
    }

    {
        int row = t >> 2, c8 = (t & 3) << 3;
        uint4 rq = *(const uint4*)(qr + qbase + (size_t)row * qstride + c8);
        *(uint4*)(&qs[row * 40 + c8]) = rq;
        uint4 rk = *(const uint4*)(kr + qbase + (size_t)row * qstride + c8);
        *(uint4*)(&ks[row * 40 + c8]) = rk;
        uint4 rv = *(const uint4*)(vin + vbase + (size_t)row * vstride + c8);
        const unsigned short* pv = (const unsigned short*)&rv;
#pragma unroll
        for (int j = 0; j < 8; ++j) vt[(c8 + j) * 72 + row] = pv[j];
    }
    __syncthreads();

    const int rsel = lane & 15;
    const int kg   = (lane >> 4) << 3;
    const int rowg = (lane >> 4) << 2;

    bf16x8 aq = *(const bf16x8*)(&qs[(wv * 16 + rsel) * 40 + kg]);
    f32x4 s[4];
#pragma unroll
    for (int j = 0; j < 4; ++j) {
        f32x4 z = {0.f, 0.f, 0.f, 0.f};
        bf16x8 bk8 = *(const bf16x8*)(&ks[(j * 16 + rsel) * 40 + kg]);
        s[j] = __builtin_amdgcn_mfma_f32_16x16x32_bf16(aq, bk8, z, 0, 0, 0);
    }

    const float* __restrict__ mrow = mask + (size_t)nh * 4096;
#pragma unroll
    for (int r = 0; r < 4; ++r) {
        const int grow = wv * 16 + rowg + r;
#pragma unroll
        for (int j = 0; j < 4; ++j)
            s[j][r] += mrow[grow * 64 + j * 16 + rsel];
        float mx = fmaxf(fmaxf(s[0][r], s[1][r]), fmaxf(s[2][r], s[3][r]));
        mx = fmaxf(mx, __shfl_xor(mx, 1));
        mx = fmaxf(mx, __shfl_xor(mx, 2));
        mx = fmaxf(mx, __shfl_xor(mx, 4));
        mx = fmaxf(mx, __shfl_xor(mx, 8));
        float e0 = __expf(s[0][r] - mx), e1 = __expf(s[1][r] - mx);
        float e2 = __expf(s[2][r] - mx), e3 = __expf(s[3][r] - mx);
        float sum = e0 + e1 + e2 + e3;
        sum += __shfl_xor(sum, 1);
        sum += __shfl_xor(sum, 2);
        sum += __shfl_xor(sum, 4);
        sum += __shfl_xor(sum, 8);
        float inv = 1.0f / sum;
        P[grow * 72 +      rsel] = f2bf(e0 * inv);
        P[grow * 72 + 16 + rsel] = f2bf(e1 * inv);
        P[grow * 72 + 32 + rsel] = f2bf(e2 * inv);
        P[grow * 72 + 48 + rsel] = f2bf(e3 * inv);
    }
    __syncthreads();

    f32x4 o[2];
#pragma unroll
    for (int n = 0; n < 2; ++n)
#pragma unroll
        for (int q = 0; q < 4; ++q) o[n][q] = 0.f;
#pragma unroll
    for (int kk = 0; kk < 2; ++kk) {
        bf16x8 ap = *(const bf16x8*)(&P[(wv * 16 + rsel) * 72 + kk * 32 + kg]);
#pragma unroll
        for (int n = 0; n < 2; ++n) {
            bf16x8 bv8 = *(const bf16x8*)(&vt[(n * 16 + rsel) * 72 + kk * 32 + kg]);
            o[n] = __builtin_amdgcn_mfma_f32_16x16x32_bf16(ap, bv8, o[n], 0, 0, 0);
        }
    }

#pragma unroll
    for (int n = 0; n < 2; ++n)
#pragma unroll
        for (int r = 0; r < 4; ++r) {
            const int grow = wv * 16 + rowg + r;
            size_t oidx = vbase + (size_t)grow * vstride + n * 16 + rsel;
            float val = o[n][r];
            if (AXIS == 1) val += bf2f(addin[oidx]);
            outp[oidx] = f2bf(val);
        }
}

// ---------------------------------------------------------------------------
// Kernel 5: output MFMA GEMM (reg-staged, R12 structure): y16 @ Wot16^T + bo
// ---------------------------------------------------------------------------
__global__ __launch_bounds__(256) void gemm_out_mfma(
    const unsigned short* __restrict__ y16, const unsigned short* __restrict__ Wot16,
    const float* __restrict__ bo, float* __restrict__ out)
{
    __shared__ __align__(16) unsigned short As[128 * 32];
    __shared__ __align__(16) unsigned short Bs[128 * 32];

    const int t = threadIdx.x;
    const int lane = t & 63, wid = t >> 6;
    const int wr = wid >> 1, wc = wid & 1;
    const int m0 = blockIdx.x * 128;
    const int n0 = blockIdx.y * 128;

    f32x4 acc[4][4];
#pragma unroll
    for (int i = 0; i < 4; ++i)
#pragma unroll
        for (int j = 0; j < 4; ++j)
#pragma unroll
            for (int q = 0; q < 4; ++q) acc[i][j][q] = 0.f;

    const int row_s = t >> 2;
    const int kp_s  = (t & 3) << 3;

    for (int ks = 0; ks < 8; ++ks) {
        const int k0 = ks * 32;
        const unsigned short* ap = y16 + (size_t)(m0 + row_s) * 256 + k0 + kp_s;
        uint4 a0 = *(const uint4*)ap;
        uint4 a1 = *(const uint4*)(ap + 64 * 256);
        const unsigned short* bp = Wot16 + (size_t)(n0 + row_s) * 256 + k0 + kp_s;
        uint4 b0 = *(const uint4*)bp;
        uint4 b1 = *(const uint4*)(bp + 64 * 256);

        __syncthreads();
        *(uint4*)(&As[swz(row_s,      kp_s)]) = a0;
        *(uint4*)(&As[swz(row_s + 64, kp_s)]) = a1;
        *(uint4*)(&Bs[swz(row_s,      kp_s)]) = b0;
        *(uint4*)(&Bs[swz(row_s + 64, kp_s)]) = b1;
        __syncthreads();

        bf16x8 af[4], bf[4];
        const int rsel = lane & 15, kg8 = (lane >> 4) << 3;
#pragma unroll
        for (int i = 0; i < 4; ++i)
            af[i] = *(const bf16x8*)(&As[swz(wr * 64 + i * 16 + rsel, kg8)]);
#pragma unroll
        for (int j = 0; j < 4; ++j)
            bf[j] = *(const bf16x8*)(&Bs[swz(wc * 64 + j * 16 + rsel, kg8)]);
#pragma unroll
        for (int i = 0; i < 4; ++i)
#pragma unroll
            for (int j = 0; j < 4; ++j)
                acc[i][j] = __builtin_amdgcn_mfma_f32_16x16x32_bf16(af[i], bf[j], acc[i][j], 0, 0, 0);
    }

    const int col_l = lane & 15, rowg = (lane >> 4) << 2;
#pragma unroll
    for (int i = 0; i < 4; ++i)
#pragma unroll
        for (int j = 0; j < 4; ++j) {
            int nn = n0 + wc * 64 + j * 16 + col_l;
            float bias = bo[nn];
#pragma unroll
            for (int r = 0; r < 4; ++r) {
                int m = m0 + wr * 64 + i * 16 + rowg + r;
                out[(size_t)m * 256 + nn] = acc[i][j][r] + bias;
            }
        }
}

// ---------------------------------------------------------------------------
extern "C" void kernel_launch(void* const* d_in, const int* in_sizes, int n_in,
                              void* d_out, int out_size, void* d_ws, size_t ws_size,
                              hipStream_t stream) {
    const float* x      = (const float*)d_in[0];
    const float* sin_t  = (const float*)d_in[1];
    const float* cos_t  = (const float*)d_in[2];
    const float* mask_h = (const float*)d_in[3];
    const float* mask_w = (const float*)d_in[4];
    const float* Wq     = (const float*)d_in[5];
    const float* bq     = (const float*)d_in[6];
    const float* Wk     = (const float*)d_in[7];
    const float* bk     = (const float*)d_in[8];
    const float* Wv     = (const float*)d_in[9];
    const float* bv     = (const float*)d_in[10];
    const float* conv_w = (const float*)d_in[11];
    const float* conv_b = (const float*)d_in[12];
    const float* Wo     = (const float*)d_in[13];
    const float* bo     = (const float*)d_in[14];

    // ws (bf16 buffers)
    unsigned short* ws    = (unsigned short*)d_ws;
    unsigned short* v16   = ws;              // (B,H,W,C)
    unsigned short* lepe16= v16 + NEL;       // (B,H,W,C)
    unsigned short* qr16  = lepe16 + NEL;    // (B,NH,H,W,KD)
    unsigned short* kr16  = qr16 + NEL;
    unsigned short* y16   = kr16 + NEL;      // (B,H,W,C)
    unsigned short* Wt16  = y16 + NEL;       // (768,256) n-major (+Wo after)
    unsigned short* Wot16 = Wt16 + 768 * 256;// (256,256) n-major

    // d_out scratch: lower half = vv16 (bf16), upper half = x16 (bf16).
    unsigned short* vv16 = (unsigned short*)d_out;
    unsigned short* x16  = (unsigned short*)d_out + NEL;

    prep_x16<<<(int)(NEL / 2048), 256, 0, stream>>>(x, x16);
    trans_all<<<128, 256, 0, stream>>>(Wq, Wk, Wv, Wo, Wt16);

    qkv_mfma<<<dim3(M_TOT / 128, 6), 256, 0, stream>>>(
        x16, Wt16, bq, bk, bv, sin_t, cos_t, qr16, kr16, v16);

    conv_kernel<<<(int)(NEL / 32 / 256), 256, 0, stream>>>(v16, conv_w, conv_b, lepe16);

    attn_mfma<0><<<B * H * NH, 256, 0, stream>>>(qr16, kr16, v16, mask_w, nullptr, vv16);

    attn_mfma<1><<<B * W * NH, 256, 0, stream>>>(qr16, kr16, vv16, mask_h, lepe16, y16);

    gemm_out_mfma<<<dim3(M_TOT / 128, 2), 256, 0, stream>>>(y16, Wot16, bo, (float*)d_out);
}